// Round 1
// baseline (259.028 us; speedup 1.0000x reference)
//
#include <hip/hip_runtime.h>

#define CIN 16
#define COUT 32
#define KK 9
#define NB 8
#define H 64
#define W 64
#define HW 4096

// out[b,o,l] = sum_{i,k} w[i,o,k] * ( silu(v) + sum_n c[i,o,k,n]*T_n(tanh(v)) )
// v = zero-padded patch value; T_n = Chebyshev polynomial (cos(n*arccos(tanh v)) identity).
__global__ __launch_bounds__(256) void kan_conv_kernel(
    const float* __restrict__ x,   // (16,16,64,64)
    const float* __restrict__ w,   // (16,32,9,1)
    const float* __restrict__ c,   // (16,32,9,1,8)
    float* __restrict__ out)       // (16,32,64,64)
{
    const int pix = blockIdx.x * blockDim.x + threadIdx.x;  // 0..65535
    const int b  = pix >> 12;
    const int l  = pix & (HW - 1);
    const int y  = l >> 6;
    const int xx = l & 63;

    float acc[COUT];
#pragma unroll
    for (int o = 0; o < COUT; ++o) acc[o] = 0.f;

    for (int i = 0; i < CIN; ++i) {
        const float* xp = x + ((size_t)(b * CIN + i)) * HW;
        for (int kh = 0; kh < 3; ++kh) {
            const int yy = y + kh - 1;
            const bool yok = (yy >= 0) & (yy < H);
            for (int kw = 0; kw < 3; ++kw) {
                const int xk = xx + kw - 1;
                const bool ok = yok & (xk >= 0) & (xk < W);
                const float v = ok ? xp[yy * W + xk] : 0.f;
                const int k = kh * 3 + kw;

                // features: u = tanh(v), s = silu(v), T_1..T_8 Chebyshev
                const float e2 = __expf(2.f * v);
                const float u  = 1.f - 2.f * __builtin_amdgcn_rcpf(e2 + 1.f);
                const float s  = v * __builtin_amdgcn_rcpf(1.f + __expf(-v));
                float T[NB];
                T[0] = u;
                T[1] = 2.f * u * u - 1.f;
#pragma unroll
                for (int n = 2; n < NB; ++n) T[n] = 2.f * u * T[n - 1] - T[n - 2];

                // weights are wave-uniform -> scalar loads
                const float* wp = w + (size_t)(i * COUT) * KK + k;        // stride KK over o
                const float* cp = c + ((size_t)(i * COUT) * KK + k) * NB; // stride KK*NB over o
#pragma unroll
                for (int o = 0; o < COUT; ++o) {
                    float tmp = s;
#pragma unroll
                    for (int n = 0; n < NB; ++n)
                        tmp = fmaf(cp[(size_t)o * KK * NB + n], T[n], tmp);
                    acc[o] = fmaf(wp[(size_t)o * KK], tmp, acc[o]);
                }
            }
        }
    }

    float* op = out + (size_t)b * COUT * HW + l;
#pragma unroll
    for (int o = 0; o < COUT; ++o) op[(size_t)o * HW] = acc[o];
}

extern "C" void kernel_launch(void* const* d_in, const int* in_sizes, int n_in,
                              void* d_out, int out_size, void* d_ws, size_t ws_size,
                              hipStream_t stream) {
    const float* x = (const float*)d_in[0];
    const float* w = (const float*)d_in[1];
    const float* c = (const float*)d_in[2];
    float* out = (float*)d_out;

    const int total = 16 * HW;                 // 65536 pixels
    const int block = 256;
    const int grid = total / block;            // 256 blocks
    kan_conv_kernel<<<grid, block, 0, stream>>>(x, w, c, out);
}